// Round 6
// baseline (184.285 us; speedup 1.0000x reference)
//
#include <hip/hip_runtime.h>

// Attention_Layer: scores=d@e^T -> softmax -> value=attn@e -> tanh([value,d]@W+b)
// B=8 TE=4096 TD=1024 H=256 NH=256, f32 in/out.
// Round 6: 32x32x16 MFMA flash (2x FLOP/operand-byte vs 16x16x32), q=32/wave,
// chunked global layouts so LDS reads are base+imm (0 VALU) and conflict-free,
// dbuf global_load_lds staging, d hi/lo resident in VGPRs, acc in AGPRs,
// fused combine+dense MFMA epilogue.

#define B_ 8
#define TE_ 4096
#define TD_ 1024
#define H_ 256
#define NS_ 8
#define CHUNK_ (TE_ / NS_)   // 512
#define NIT_ (CHUNK_ / 32)   // 16
#define NROW_ (B_ * TD_)     // 8192

typedef __attribute__((ext_vector_type(8))) short s16x8;
typedef __attribute__((ext_vector_type(4))) float fx4;
typedef __attribute__((ext_vector_type(16))) float fx16;
typedef __attribute__((ext_vector_type(4))) unsigned short u16x4;

#define MFMA32(a, b, c) __builtin_amdgcn_mfma_f32_32x32x16_bf16(a, b, c, 0, 0, 0)

__device__ __forceinline__ unsigned short f2bf(float x) {
  unsigned u = __float_as_uint(x);
  unsigned r = (u + 0x7fffu + ((u >> 16) & 1u)) >> 16;  // RNE
  return (unsigned short)r;
}
__device__ __forceinline__ float bf2f(unsigned short s) {
  return __uint_as_float(((unsigned)s) << 16);
}
// pack two bf16-representable f32 into one u32 (lo = f0, hi = f1)
__device__ __forceinline__ unsigned pk2(float f0, float f1) {
  return (__float_as_uint(f0) >> 16) | (__float_as_uint(f1) & 0xFFFF0000u);
}
__device__ __forceinline__ void gload_lds16(const void* g, void* l) {
  __builtin_amdgcn_global_load_lds(
      (const __attribute__((address_space(1))) void*)g,
      (__attribute__((address_space(3))) void*)l, 16, 0, 0);
}

// ---------------- prep: e -> ehi/elo [b][H/8][TE][8], eT [b][TE/8][H][8];
//                  W -> WT bf16 [256n][512k]
__global__ __launch_bounds__(256) void prep(const float* __restrict__ e,
                                            const float* __restrict__ W,
                                            unsigned short* __restrict__ ehi,
                                            unsigned short* __restrict__ elo,
                                            unsigned short* __restrict__ eT,
                                            unsigned short* __restrict__ WT) {
  __shared__ unsigned short lt_h[64][65];
  __shared__ unsigned short lt_l[64][65];
  __shared__ float wl[32][33];
  const int bid = blockIdx.x;
  const int tid = threadIdx.x;
  if (bid < 2048) {                   // e part: 8 b * 64 s-tiles * 4 h-tiles
    const int b = bid >> 8;
    const int s0 = ((bid >> 2) & 63) * 64;
    const int h0 = (bid & 3) * 64;
#pragma unroll
    for (int i = 0; i < 4; ++i) {
      const int row = (tid >> 4) + 16 * i;     // s-local
      const int col = (tid & 15) * 4;          // h-local
      const size_t go = (((size_t)b * TE_) + s0 + row) * H_ + h0 + col;
      const fx4 v = *(const fx4*)&e[go];
#pragma unroll
      for (int j = 0; j < 4; ++j) {
        const unsigned short hb = f2bf(v[j]);
        lt_h[row][col + j] = hb;
        lt_l[row][col + j] = f2bf(v[j] - bf2f(hb));
      }
    }
    __syncthreads();
    const int hc = tid >> 5;          // 0..7 (h-chunk of 8)
    const int sg = (tid & 31) * 2;    // s-local pair
    // ehi/elo: [b][H/8][TE][8]
#pragma unroll
    for (int p = 0; p < 2; ++p) {
      const int ss = sg + p;
      s16x8 vh, vl;
#pragma unroll
      for (int j = 0; j < 8; ++j) {
        vh[j] = (short)lt_h[ss][hc * 8 + j];
        vl[j] = (short)lt_l[ss][hc * 8 + j];
      }
      const size_t dst = (((size_t)b * 32 + (h0 >> 3) + hc) * TE_ + s0 + ss) * 8;
      *(s16x8*)&ehi[dst] = vh;
      *(s16x8*)&elo[dst] = vl;
    }
    // eT: [b][TE/8][H][8]
    const int sc = tid >> 5;          // 0..7 (s-chunk of 8)
    const int hg = (tid & 31) * 2;    // h-local pair
#pragma unroll
    for (int p = 0; p < 2; ++p) {
      const int hh = hg + p;
      s16x8 v;
#pragma unroll
      for (int j = 0; j < 8; ++j) v[j] = (short)lt_h[sc * 8 + j][hh];
      const size_t dst = (((size_t)b * (TE_ / 8) + (s0 >> 3) + sc) * H_ + h0 + hh) * 8;
      *(s16x8*)&eT[dst] = v;
    }
  } else {                            // W part: 128 tiles of 32x32
    const int tb = bid - 2048;
    const int k0 = (tb >> 3) * 32, n0 = (tb & 7) * 32;
    const int r = tid >> 3, c4 = (tid & 7) * 4;
    const fx4 v = *(const fx4*)&W[(size_t)(k0 + r) * 256 + n0 + c4];
#pragma unroll
    for (int j = 0; j < 4; ++j) wl[r][c4 + j] = v[j];
    __syncthreads();
    u16x4 o;
#pragma unroll
    for (int j = 0; j < 4; ++j) o[j] = f2bf(wl[c4 + j][r]);
    *(u16x4*)&WT[(size_t)(n0 + r) * 512 + k0 + c4] = o;
  }
}

// ---------------- flash6: 256 blocks = b(8)|qb(4)|ns(8); 8 waves x 32 q
__global__ __launch_bounds__(512) void flash6(
    const unsigned short* __restrict__ ehi_g, const unsigned short* __restrict__ elo_g,
    const unsigned short* __restrict__ eT_g, const float* __restrict__ dmat,
    unsigned short* __restrict__ pacc, float* __restrict__ pm,
    float* __restrict__ pl) {
  const int bid = blockIdx.x;
  const int ns = bid & 7;             // low bits -> XCD affinity for the chunk
  const int qb = (bid >> 3) & 3;
  const int b = bid >> 5;
  const int tid = threadIdx.x;
  const int w = tid >> 6;
  const int lane = tid & 63;
  const int ln = lane & 31, hi = lane >> 5;
  const int q = qb * 256 + w * 32 + ln;
  const size_t R = (size_t)b * TD_ + q;

  __shared__ uint4 smem[2][3][1024];  // 96 KB: dbuf x {ehi, elo, eT}

  // ---- staging pointers (coalesced: consecutive lanes = consecutive addr)
  const size_t sb = (size_t)ns * CHUNK_;
  const unsigned short *peh0, *peh1, *pel0, *pel1, *pet0, *pet1;
  {
    const size_t eb0 = (((size_t)b * 32 + (tid >> 5)) * TE_ + sb + (tid & 31)) * 8;
    const size_t eb1 = (((size_t)b * 32 + (tid >> 5) + 16) * TE_ + sb + (tid & 31)) * 8;
    peh0 = ehi_g + eb0; peh1 = ehi_g + eb1;
    pel0 = elo_g + eb0; pel1 = elo_g + eb1;
    const size_t tb0 = (((size_t)b * (TE_ / 8) + (sb >> 3) + (tid >> 8)) * H_ + (tid & 255)) * 8;
    const size_t tb1 = (((size_t)b * (TE_ / 8) + (sb >> 3) + ((tid + 512) >> 8)) * H_ + (tid & 255)) * 8;
    pet0 = eT_g + tb0; pet1 = eT_g + tb1;
  }
  auto STAGE = [&](int buf) {
    uint4* eh = smem[buf][0];
    uint4* el = smem[buf][1];
    uint4* et = smem[buf][2];
    gload_lds16(peh0, &eh[tid]); gload_lds16(peh1, &eh[tid + 512]);
    gload_lds16(pel0, &el[tid]); gload_lds16(pel1, &el[tid + 512]);
    gload_lds16(pet0, &et[tid]); gload_lds16(pet1, &et[tid + 512]);
    peh0 += 32 * 8; peh1 += 32 * 8;       // s += 32
    pel0 += 32 * 8; pel1 += 32 * 8;
    pet0 += 4 * H_ * 8; pet1 += 4 * H_ * 8;  // s-chunk += 4
  };

  STAGE(0);                           // tile 0 in flight during d-preload

  // ---- d B-frags hi/lo resident in VGPRs: B[k=kk*16+hi*8+j][n=q]
  s16x8 bdh[16], bdl[16];
  {
    const float* dr = dmat + R * H_ + hi * 8;
#pragma unroll
    for (int kk = 0; kk < 16; ++kk) {
      const fx4 x0 = *(const fx4*)(dr + kk * 16);
      const fx4 x1 = *(const fx4*)(dr + kk * 16 + 4);
      s16x8 hh, ll;
#pragma unroll
      for (int j = 0; j < 4; ++j) {
        unsigned short hb = f2bf(x0[j]);
        hh[j] = (short)hb; ll[j] = (short)f2bf(x0[j] - bf2f(hb));
        hb = f2bf(x1[j]);
        hh[4 + j] = (short)hb; ll[4 + j] = (short)f2bf(x1[j] - bf2f(hb));
      }
      bdh[kk] = hh; bdl[kk] = ll;
    }
  }

  fx16 acc[8];
#pragma unroll
  for (int nt = 0; nt < 8; ++nt)
#pragma unroll
    for (int r = 0; r < 16; ++r) acc[nt][r] = 0.f;
  float m = -__builtin_inff(), l = 0.f;

  __syncthreads();                    // tile 0 resident

  for (int it = 0; it < NIT_; ++it) {
    const int cur = it & 1;
    if (it + 1 < NIT_) STAGE(cur ^ 1);   // prefetch next tile (drained at barrier)

    const uint4* ehb = smem[cur][0];
    const uint4* elb = smem[cur][1];
    const uint4* etb = smem[cur][2];
    const uint4* eAh = ehb + hi * 32 + ln;   // + kk*64 (imm) per kstep
    const uint4* eAl = elb + hi * 32 + ln;

    // ---- QK^T (swapped): S^T[32s][32q] = e(A, LDS) x d(B, regs); 2 acc chains
    fx16 saA, saB;
#pragma unroll
    for (int r = 0; r < 16; ++r) { saA[r] = 0.f; saB[r] = 0.f; }
#pragma unroll
    for (int kk = 0; kk < 16; ++kk) {
      const s16x8 ah = *(const s16x8*)(eAh + kk * 64);
      const s16x8 al = *(const s16x8*)(eAl + kk * 64);
      saA = MFMA32(ah, bdh[kk], saA);
      saB = MFMA32(al, bdh[kk], saB);
      saB = MFMA32(ah, bdl[kk], saB);
    }
    fx16 sa;
#pragma unroll
    for (int r = 0; r < 16; ++r) sa[r] = saA[r] + saB[r];

    // ---- online softmax (col q=ln: 16 regs + hi-pair -> 1 shfl_xor(32))
    float mx = sa[0];
#pragma unroll
    for (int r = 1; r < 16; ++r) mx = fmaxf(mx, sa[r]);
    mx = fmaxf(mx, __shfl_xor(mx, 32, 64));
    if (!__all(mx <= m + 4.0f)) {      // defer-max
      const float nm = fmaxf(m, mx);
      const float sc = __expf(m - nm);
      m = nm; l *= sc;
#pragma unroll
      for (int nt = 0; nt < 8; ++nt)
#pragma unroll
        for (int r = 0; r < 16; ++r) acc[nt][r] *= sc;
    }
    float t[16];
    float rs = 0.f;
#pragma unroll
    for (int r = 0; r < 16; ++r) {
      t[r] = bf2f(f2bf(__expf(sa[r] - m)));   // RNE bf16-rounded P
      rs += t[r];
    }
    rs += __shfl_xor(rs, 32, 64);
    l += rs;

    // ---- pack P^T bf16: rows (r&3)+8*(r>>2)+4*hi
    unsigned pku[2][4];
    pku[0][0] = pk2(t[0], t[1]);  pku[0][1] = pk2(t[2], t[3]);
    pku[0][2] = pk2(t[4], t[5]);  pku[0][3] = pk2(t[6], t[7]);
    pku[1][0] = pk2(t[8], t[9]);  pku[1][1] = pk2(t[10], t[11]);
    pku[1][2] = pk2(t[12], t[13]); pku[1][3] = pk2(t[14], t[15]);

    // ---- PV: value^T[h][q] += eT(A) x P^T(B); B-frag via one lane^32 swap
    const uint4* eP = etb + hi * 256 + ln;   // + ks*512 + nt*32 (imm)
#pragma unroll
    for (int ks = 0; ks < 2; ++ks) {
      const unsigned P0 = pku[ks][0], P1 = pku[ks][1];
      const unsigned P2 = pku[ks][2], P3 = pku[ks][3];
      const unsigned x0 = hi ? P0 : P2;
      const unsigned x1 = hi ? P1 : P3;
      const unsigned r0 = __shfl_xor(x0, 32, 64);
      const unsigned r1 = __shfl_xor(x1, 32, 64);
      union { unsigned u[4]; s16x8 v; } pf;
      pf.u[0] = hi ? r0 : P0; pf.u[1] = hi ? r1 : P1;
      pf.u[2] = hi ? P2 : r0; pf.u[3] = hi ? P3 : r1;
#pragma unroll
      for (int nt = 0; nt < 8; ++nt) {
        const s16x8 ea = *(const s16x8*)(eP + ks * 512 + nt * 32);
        acc[nt] = MFMA32(ea, pf.v, acc[nt]);
      }
    }
    __syncthreads();                  // drains prefetch; next tile resident
  }

  // ---- bf16 partials (unnormalized) + (m,l) per q
  unsigned short* pr = pacc + (((size_t)ns * NROW_) + R) * H_;
#pragma unroll
  for (int nt = 0; nt < 8; ++nt) {
#pragma unroll
    for (int qd = 0; qd < 4; ++qd) {
      u16x4 o;
#pragma unroll
      for (int j = 0; j < 4; ++j) o[j] = f2bf(acc[nt][qd * 4 + j]);
      *(u16x4*)(pr + nt * 32 + qd * 8 + hi * 4) = o;
    }
  }
  if (hi == 0) {
    pm[ns * NROW_ + R] = m;
    pl[ns * NROW_ + R] = l;
  }
}

// ---------------- dense2: combine NS partials -> X=[value,d] bf16 -> MFMA -> tanh
__global__ __launch_bounds__(256) void dense2(const unsigned short* __restrict__ pacc,
                                              const float* __restrict__ pm,
                                              const float* __restrict__ pl,
                                              const float* __restrict__ dmat,
                                              const unsigned short* __restrict__ WT,
                                              const float* __restrict__ bias,
                                              float* __restrict__ out) {
  const int row0 = blockIdx.x * 32;    // 256 blocks
  const int tid = threadIdx.x;
  const int w = tid >> 6;
  const int lane = tid & 63;
  const int ln = lane & 31, hi = lane >> 5;
  __shared__ unsigned short Xl[32][520];

  {
    const int row = tid >> 3;
    const int c0 = (tid & 7) * 32;
    const int R = row0 + row;
    float wts[NS_];
    float M = -__builtin_inff();
#pragma unroll
    for (int s = 0; s < NS_; ++s) M = fmaxf(M, pm[s * NROW_ + R]);
    float L = 0.f;
#pragma unroll
    for (int s = 0; s < NS_; ++s) {
      wts[s] = __expf(pm[s * NROW_ + R] - M);
      L += wts[s] * pl[s * NROW_ + R];
    }
    const float inv = 1.0f / L;
#pragma unroll
    for (int c8 = 0; c8 < 4; ++c8) {
      const int cc = c0 + c8 * 8;
      float o8[8];
#pragma unroll
      for (int j = 0; j < 8; ++j) o8[j] = 0.f;
#pragma unroll
      for (int s = 0; s < NS_; ++s) {
        const s16x8 v = *(const s16x8*)&pacc[(((size_t)s * NROW_) + R) * H_ + cc];
#pragma unroll
        for (int j = 0; j < 8; ++j)
          o8[j] += wts[s] * bf2f((unsigned short)v[j]);
      }
      u16x4 y0, y1;
#pragma unroll
      for (int j = 0; j < 4; ++j) {
        y0[j] = f2bf(o8[j] * inv);
        y1[j] = f2bf(o8[4 + j] * inv);
      }
      *(u16x4*)&Xl[row][cc] = y0;
      *(u16x4*)&Xl[row][cc + 4] = y1;
    }
    const float* drow = dmat + (size_t)R * H_ + c0;
#pragma unroll
    for (int c8 = 0; c8 < 8; ++c8) {
      const fx4 v = *(const fx4*)&drow[c8 * 4];
      u16x4 y;
#pragma unroll
      for (int j = 0; j < 4; ++j) y[j] = f2bf(v[j]);
      *(u16x4*)&Xl[row][256 + c0 + c8 * 4] = y;
    }
  }
  __syncthreads();

  fx16 a0, a1;
#pragma unroll
  for (int r = 0; r < 16; ++r) { a0[r] = 0.f; a1[r] = 0.f; }
  const int n0 = w * 64;
#pragma unroll
  for (int ks = 0; ks < 32; ++ks) {
    const s16x8 av = *(const s16x8*)&Xl[ln][ks * 16 + hi * 8];
    const s16x8 b0 = *(const s16x8*)(WT + (size_t)(n0 + ln) * 512 + ks * 16 + hi * 8);
    const s16x8 b1 = *(const s16x8*)(WT + (size_t)(n0 + 32 + ln) * 512 + ks * 16 + hi * 8);
    a0 = MFMA32(av, b0, a0);
    a1 = MFMA32(av, b1, a1);
  }
  const float bn0 = bias[n0 + ln];
  const float bn1 = bias[n0 + 32 + ln];
#pragma unroll
  for (int r = 0; r < 16; ++r) {
    const int rloc = (r & 3) + 8 * (r >> 2) + 4 * hi;
    const size_t ro = (size_t)(row0 + rloc) * 256;
    out[ro + n0 + ln] = tanhf(a0[r] + bn0);
    out[ro + n0 + 32 + ln] = tanhf(a1[r] + bn1);
  }
}

extern "C" void kernel_launch(void* const* d_in, const int* in_sizes, int n_in,
                              void* d_out, int out_size, void* d_ws, size_t ws_size,
                              hipStream_t stream) {
  const float* e = (const float*)d_in[0];    // [8,4096,256]
  const float* d = (const float*)d_in[1];    // [8,1024,256]
  const float* W = (const float*)d_in[2];    // [512,256]
  const float* bias = (const float*)d_in[3]; // [256]
  float* out = (float*)d_out;

  char* p = (char*)d_ws;
  const size_t EB = (size_t)B_ * TE_ * H_ * 2;       // 16 MiB
  const size_t WB = (size_t)512 * 256 * 2;           // 256 KiB
  const size_t PB = (size_t)NS_ * NROW_ * H_ * 2;    // 32 MiB (bf16 partials)
  unsigned short* ehi = (unsigned short*)p;            p += EB;
  unsigned short* elo = (unsigned short*)p;            p += EB;
  unsigned short* eT  = (unsigned short*)p;            p += EB;
  unsigned short* WT  = (unsigned short*)p;            p += WB;
  unsigned short* pacc = (unsigned short*)p;           p += PB;
  float* pmv = (float*)p;                              p += (size_t)NS_ * NROW_ * 4;
  float* plv = (float*)p;                              // total ~80.8 MiB

  prep<<<dim3(2176), dim3(256), 0, stream>>>(e, W, ehi, elo, eT, WT);
  flash6<<<dim3(256), dim3(512), 0, stream>>>(ehi, elo, eT, d, pacc, pmv, plv);
  dense2<<<dim3(256), dim3(256), 0, stream>>>(pacc, pmv, plv, d, WT, bias, out);
}